// Round 2
// baseline (786.825 us; speedup 1.0000x reference)
//
#include <hip/hip_runtime.h>
#include <hip/hip_bf16.h>
#include <stdint.h>

#define NN 100000   // nodes
#define NE 640000   // edges
#define DD 128      // features
#define BN_EPS 1e-5f

typedef __attribute__((ext_vector_type(8))) short bf16x8;
typedef __attribute__((ext_vector_type(4))) float f32x4;

static __device__ __forceinline__ unsigned short f2bf(float f) {
  unsigned u = __float_as_uint(f);
  u += 0x7FFFu + ((u >> 16) & 1u);   // RNE
  return (unsigned short)(u >> 16);
}
static __device__ __forceinline__ bf16x8 cvt8(const float* p, float mul) {
  bf16x8 r;
#pragma unroll
  for (int i = 0; i < 8; ++i) r[i] = (short)f2bf(p[i] * mul);
  return r;
}

// ---------------- scatter: agg[dst] += relu(x[src]); cnt[dst] += 1 ----------------
// 64 threads per edge, 2 f32 features per thread (one 8B gather per thread).
__global__ __launch_bounds__(256) void k_scatter(
    const float* __restrict__ x, const int* __restrict__ ei,
    float* __restrict__ agg, float* __restrict__ cnt)
{
  long t = (long)blockIdx.x * 256 + threadIdx.x;
  int e = (int)(t >> 6);
  if (e >= NE) return;
  int f2 = ((int)t & 63) * 2;
  int s = ei[e];        // src row of edge_index [2][E]
  int d = ei[NE + e];   // dst row
  float2 v = *(const float2*)(x + (long)s * DD + f2);
  float v0 = fmaxf(v.x, 0.f);
  float v1 = fmaxf(v.y, 0.f);
  float* ap = agg + (long)d * DD + f2;
  atomicAdd(ap, v0);
  atomicAdd(ap + 1, v1);
  if (f2 == 0) atomicAdd(cnt + d, 1.0f);
}

// ---------------- fused K=256 GEMM: out_pre = [mean_agg | relu(x)] @ [W_l | W_r]^T + b_l
// block = 4 waves, 64 rows x 128 cols; wave w: rows w*16..w*16+15.
// mfma_f32_16x16x32_bf16: A row = lane&15, k = (lane>>4)*8 + e (contiguous 8)
//                         C/D col = lane&15, row = (lane>>4)*4 + reg   [m89-verified]
__global__ __launch_bounds__(256) void k_gemm(
    const float* __restrict__ x,
    const float* __restrict__ agg, const float* __restrict__ cnt,
    const float* __restrict__ Wl, const float* __restrict__ Wr,
    const float* __restrict__ bl,
    float* __restrict__ outpre)
{
  int lane = threadIdx.x & 63;
  int wv   = threadIdx.x >> 6;
  int c15  = lane & 15;
  int kg   = lane >> 4;                       // 0..3
  int rowA = blockIdx.x * 64 + wv * 16 + c15; // A-fragment row
  bool rowAok = rowA < NN;
  float rinv = 0.f;
  if (rowAok) rinv = 1.0f / fmaxf(cnt[rowA], 1.0f);

  f32x4 acc[8];
  f32x4 zero = {0.f, 0.f, 0.f, 0.f};
#pragma unroll
  for (int i = 0; i < 8; ++i) acc[i] = zero;

#pragma unroll
  for (int ks = 0; ks < 8; ++ks) {
    int k0 = ks * 32 + kg * 8;                // 0..248 over K=256
    bf16x8 a = {};
    if (rowAok) {
      if (k0 < DD) {
        // mean-aggregated neighbors (f32 -> bf16)
        float tmp[8];
        *(float4*)(tmp)     = *(const float4*)(agg + (long)rowA * DD + k0);
        *(float4*)(tmp + 4) = *(const float4*)(agg + (long)rowA * DD + k0 + 4);
        a = cvt8(tmp, rinv);
      } else {
        // root term h = relu(x)
        float tmp[8];
        *(float4*)(tmp)     = *(const float4*)(x + (long)rowA * DD + (k0 - DD));
        *(float4*)(tmp + 4) = *(const float4*)(x + (long)rowA * DD + (k0 - DD) + 4);
#pragma unroll
        for (int i = 0; i < 8; ++i) tmp[i] = fmaxf(tmp[i], 0.f);
        a = cvt8(tmp, 1.0f);
      }
    }
    const float* W = (k0 < DD) ? Wl : Wr;
    int kk = k0 & (DD - 1);
#pragma unroll
    for (int ct = 0; ct < 8; ++ct) {
      float tmp[8];
      const float* wp = W + (long)(ct * 16 + c15) * DD + kk;
      *(float4*)(tmp)     = *(const float4*)(wp);
      *(float4*)(tmp + 4) = *(const float4*)(wp + 4);
      bf16x8 b = cvt8(tmp, 1.0f);
      acc[ct] = __builtin_amdgcn_mfma_f32_16x16x32_bf16(a, b, acc[ct], 0, 0, 0);
    }
  }

  int rbase = blockIdx.x * 64 + wv * 16 + kg * 4;
#pragma unroll
  for (int ct = 0; ct < 8; ++ct) {
    int col = ct * 16 + c15;
    float bias = bl[col];
#pragma unroll
    for (int r = 0; r < 4; ++r) {
      int row = rbase + r;
      if (row < NN)
        outpre[(long)row * DD + col] = acc[ct][r] + bias;
    }
  }
}

// ---------------- per-feature partial sums over rows ----------------
__global__ __launch_bounds__(256) void k_colstats(
    const float* __restrict__ outpre, float* __restrict__ partials)
{
  int c  = threadIdx.x & 127;
  int vb = blockIdx.x * 2 + (threadIdx.x >> 7);   // 0..1023 virtual blocks
  float s = 0.f, q = 0.f;
  for (int r = vb; r < NN; r += 1024) {
    float v = outpre[(long)r * DD + c];
    s += v; q += v * v;
  }
  partials[vb * 256 + c] = s;
  partials[vb * 256 + 128 + c] = q;
}

// ---------------- reduce partials -> scale/shift ----------------
__global__ __launch_bounds__(1024) void k_finalize(
    const float* __restrict__ partials,
    const float* __restrict__ gamma, const float* __restrict__ beta,
    float* __restrict__ ss)
{
  __shared__ float ls[8][128], lq[8][128];
  int c  = threadIdx.x & 127;
  int sl = threadIdx.x >> 7;   // 0..7
  float s = 0.f, q = 0.f;
  for (int b = sl * 128; b < (sl + 1) * 128; ++b) {
    s += partials[b * 256 + c];
    q += partials[b * 256 + 128 + c];
  }
  ls[sl][c] = s; lq[sl][c] = q;
  __syncthreads();
  if (sl == 0) {
    float S = 0.f, Q = 0.f;
#pragma unroll
    for (int i = 0; i < 8; ++i) { S += ls[i][c]; Q += lq[i][c]; }
    float mu  = S / (float)NN;
    float var = Q / (float)NN - mu * mu;    // biased variance (training-mode BN)
    float rsig = rsqrtf(var + BN_EPS);
    float sc = gamma[c] * rsig;
    float sh = beta[c] - mu * sc;
    ss[c] = sc;
    ss[128 + c] = sh;
  }
}

// ---------------- in-place normalize on d_out ----------------
__global__ __launch_bounds__(256) void k_norm(
    float* __restrict__ io, const float* __restrict__ ss)
{
  __shared__ float sc[128], sh[128];
  if (threadIdx.x < 128) {
    sc[threadIdx.x] = ss[threadIdx.x];
    sh[threadIdx.x] = ss[128 + threadIdx.x];
  }
  __syncthreads();
  const long total = (long)NN * DD / 4;
  for (long i = (long)blockIdx.x * blockDim.x + threadIdx.x; i < total;
       i += (long)gridDim.x * blockDim.x) {
    float4 v = *(const float4*)(io + i * 4);
    int c0 = (int)((i * 4) & (DD - 1));
    v.x = fmaf(v.x, sc[c0 + 0], sh[c0 + 0]);
    v.y = fmaf(v.y, sc[c0 + 1], sh[c0 + 1]);
    v.z = fmaf(v.z, sc[c0 + 2], sh[c0 + 2]);
    v.w = fmaf(v.w, sc[c0 + 3], sh[c0 + 3]);
    *(float4*)(io + i * 4) = v;
  }
}

extern "C" void kernel_launch(void* const* d_in, const int* in_sizes, int n_in,
                              void* d_out, int out_size, void* d_ws, size_t ws_size,
                              hipStream_t stream)
{
  const float* x     = (const float*)d_in[0];
  // d_in[1] = edge_attr — unused by the reference
  const float* Wl    = (const float*)d_in[2];
  const float* bl    = (const float*)d_in[3];
  const float* Wr    = (const float*)d_in[4];
  const float* gamma = (const float*)d_in[5];
  const float* beta  = (const float*)d_in[6];
  const int*   ei    = (const int*)d_in[7];
  float* out = (float*)d_out;

  char* ws = (char*)d_ws;
  float* agg      = (float*)ws;                   // NN*DD f32   = 51,200,000 B
  float* cnt      = (float*)(ws + 51200000);      // NN f32      =    400,000 B
  float* partials = (float*)(ws + 51600000);      // 1024*256 f32= 1,048,576 B
  float* ssbuf    = (float*)(ws + 52648576);      // 256 f32
  (void)ws_size; (void)in_sizes; (void)n_in; (void)out_size;

  hipMemsetAsync(agg, 0, 51600000, stream);                   // zero agg + cnt
  k_scatter <<<160000, 256, 0, stream>>>(x, ei, agg, cnt);    // NE*64 threads
  k_gemm    <<<1563,   256, 0, stream>>>(x, agg, cnt, Wl, Wr, bl, out);
  k_colstats<<<512,    256, 0, stream>>>(out, partials);
  k_finalize<<<1,     1024, 0, stream>>>(partials, gamma, beta, ssbuf);
  k_norm    <<<2048,   256, 0, stream>>>(out, ssbuf);
}

// Round 3
// 293.229 us; speedup vs baseline: 2.6833x; 2.6833x over previous
//
#include <hip/hip_runtime.h>
#include <hip/hip_bf16.h>
#include <stdint.h>

#define NN 100000   // nodes
#define NE 640000   // edges
#define DD 128      // features
#define BN_EPS 1e-5f
#define NB 391      // scan blocks: 391*256 = 100096 >= NN

typedef __attribute__((ext_vector_type(8))) short bf16x8;
typedef __attribute__((ext_vector_type(4))) float f32x4;

static __device__ __forceinline__ float bf2f(unsigned short s) {
  return __uint_as_float(((unsigned)s) << 16);
}
static __device__ __forceinline__ unsigned short f2bf(float f) {
  unsigned u = __float_as_uint(f);
  u += 0x7FFFu + ((u >> 16) & 1u);   // RNE
  return (unsigned short)(u >> 16);
}

// ---- 1. degree histogram: deg[dst]++ -------------------------------------
__global__ __launch_bounds__(256) void k_hist(const int* __restrict__ ei,
                                              int* __restrict__ deg)
{
  int e = blockIdx.x * 256 + threadIdx.x;
  if (e < NE) atomicAdd(deg + ei[NE + e], 1);
}

// ---- 2. block sums of deg ------------------------------------------------
__global__ __launch_bounds__(256) void k_scan1(const int* __restrict__ deg,
                                               int* __restrict__ bsum)
{
  __shared__ int sc[256];
  int t = threadIdx.x;
  sc[t] = deg[blockIdx.x * 256 + t];
  __syncthreads();
  for (int s = 128; s > 0; s >>= 1) {
    if (t < s) sc[t] += sc[t + s];
    __syncthreads();
  }
  if (t == 0) bsum[blockIdx.x] = sc[0];
}

// ---- 3. exclusive scan of block sums (1 block, 512 thr) ------------------
__global__ __launch_bounds__(512) void k_scan2(const int* __restrict__ bsum,
                                               int* __restrict__ boff)
{
  __shared__ int sc[512];
  int t = threadIdx.x;
  int v = (t < NB) ? bsum[t] : 0;
  sc[t] = v;
  __syncthreads();
  for (int s = 1; s < 512; s <<= 1) {
    int add = (t >= s) ? sc[t - s] : 0;
    __syncthreads();
    sc[t] += add;
    __syncthreads();
  }
  if (t < NB) boff[t] = sc[t] - v;   // exclusive
}

// ---- 4. per-element exclusive scan -> offs; init cursor(=deg buf) --------
__global__ __launch_bounds__(256) void k_scan3(int* __restrict__ deg,
                                               const int* __restrict__ boff,
                                               int* __restrict__ offs)
{
  __shared__ int sc[256];
  int t = threadIdx.x;
  int i = blockIdx.x * 256 + t;
  int v = deg[i];
  sc[t] = v;
  __syncthreads();
  for (int s = 1; s < 256; s <<= 1) {
    int add = (t >= s) ? sc[t - s] : 0;
    __syncthreads();
    sc[t] += add;
    __syncthreads();
  }
  int excl = sc[t] - v + boff[blockIdx.x];
  offs[i] = excl;
  deg[i]  = excl;    // reuse deg as fill-cursor
}

// ---- 5. fill CSR: esrc[slot] = src ---------------------------------------
__global__ __launch_bounds__(256) void k_fill(const int* __restrict__ ei,
                                              int* __restrict__ cursor,
                                              int* __restrict__ esrc)
{
  int e = blockIdx.x * 256 + threadIdx.x;
  if (e >= NE) return;
  int pos = atomicAdd(cursor + ei[NE + e], 1);
  esrc[pos] = ei[e];
}

// ---- 6. gather-aggregate: magg[dst] = mean(relu(x[src])) as bf16 ---------
// one wave per dst; 64 lanes x float2 = one 512B row per edge.
__global__ __launch_bounds__(256) void k_agg(const float* __restrict__ x,
                                             const int* __restrict__ offs,
                                             const int* __restrict__ esrc,
                                             unsigned short* __restrict__ magg)
{
  int dst = blockIdx.x * 4 + (threadIdx.x >> 6);
  if (dst >= NN) return;
  int lane = threadIdx.x & 63;
  int off = offs[dst], end = offs[dst + 1];
  float ax = 0.f, ay = 0.f;
  for (int base = off; base < end; base += 64) {
    int m = end - base; if (m > 64) m = 64;
    int myidx = base + lane;
    int mysrc = (myidx < end) ? esrc[myidx] : 0;
    for (int j = 0; j < m; ++j) {
      int src = __shfl(mysrc, j);
      float2 v = *(const float2*)(x + (long)src * DD + lane * 2);
      ax += fmaxf(v.x, 0.f);
      ay += fmaxf(v.y, 0.f);
    }
  }
  float rinv = (end > off) ? 1.0f / (float)(end - off) : 0.f;
  unsigned pk = (unsigned)f2bf(ax * rinv) | ((unsigned)f2bf(ay * rinv) << 16);
  *(unsigned*)(magg + (long)dst * DD + lane * 2) = pk;
}

// ---- 7. prep weights: f32 -> bf16, [W_l rows | W_r rows] -----------------
__global__ __launch_bounds__(256) void k_prepw(const float* __restrict__ Wl,
                                               const float* __restrict__ Wr,
                                               unsigned short* __restrict__ wbf)
{
  int i = blockIdx.x * 256 + threadIdx.x;   // grid 128 -> 32768
  float v = (i < DD * DD) ? Wl[i] : Wr[i - DD * DD];
  wbf[i] = f2bf(v);
}

// ---- 8. fused K=256 GEMM: out = [magg | relu(x)] @ [Wl | Wr]^T + bl ------
// mfma_f32_16x16x32_bf16: A row = lane&15, k = (lane>>4)*8 + e
//                         C/D col = lane&15, row = (lane>>4)*4 + reg
__global__ __launch_bounds__(256) void k_gemm(
    const float* __restrict__ x, const unsigned short* __restrict__ magg,
    const unsigned short* __restrict__ wbf, const float* __restrict__ bl,
    float* __restrict__ outpre)
{
  int lane = threadIdx.x & 63;
  int wv   = threadIdx.x >> 6;
  int c15  = lane & 15;
  int kg   = lane >> 4;                       // 0..3
  int rowA = blockIdx.x * 64 + wv * 16 + c15;
  bool ok = rowA < NN;

  f32x4 acc[8];
  f32x4 zero = {0.f, 0.f, 0.f, 0.f};
#pragma unroll
  for (int i = 0; i < 8; ++i) acc[i] = zero;

#pragma unroll
  for (int ks = 0; ks < 8; ++ks) {
    int k0 = ks * 32 + kg * 8;                // 0..248 over K=256
    bf16x8 a = {};
    if (ok) {
      if (k0 < DD) {
        a = *(const bf16x8*)(magg + (long)rowA * DD + k0);   // bf16 mean-agg
      } else {
        float tmp[8];
        const float* xp = x + (long)rowA * DD + (k0 - DD);
        *(float4*)(tmp)     = *(const float4*)(xp);
        *(float4*)(tmp + 4) = *(const float4*)(xp + 4);
#pragma unroll
        for (int i = 0; i < 8; ++i) tmp[i] = fmaxf(tmp[i], 0.f);
#pragma unroll
        for (int i = 0; i < 8; ++i) a[i] = (short)f2bf(tmp[i]);
      }
    }
    const unsigned short* W = wbf + ((k0 < DD) ? 0 : DD * DD);
    int kk = k0 & (DD - 1);
#pragma unroll
    for (int ct = 0; ct < 8; ++ct) {
      bf16x8 b = *(const bf16x8*)(W + (long)(ct * 16 + c15) * DD + kk);
      acc[ct] = __builtin_amdgcn_mfma_f32_16x16x32_bf16(a, b, acc[ct], 0, 0, 0);
    }
  }

  int rbase = blockIdx.x * 64 + wv * 16 + kg * 4;
#pragma unroll
  for (int ct = 0; ct < 8; ++ct) {
    int col = ct * 16 + c15;
    float bias = bl[col];
#pragma unroll
    for (int r = 0; r < 4; ++r) {
      int row = rbase + r;
      if (row < NN)
        outpre[(long)row * DD + col] = acc[ct][r] + bias;
    }
  }
}

// ---- 9. per-feature partial sums -----------------------------------------
__global__ __launch_bounds__(256) void k_colstats(
    const float* __restrict__ outpre, float* __restrict__ partials)
{
  int c  = threadIdx.x & 127;
  int vb = blockIdx.x * 2 + (threadIdx.x >> 7);   // 0..1023
  float s = 0.f, q = 0.f;
  for (int r = vb; r < NN; r += 1024) {
    float v = outpre[(long)r * DD + c];
    s += v; q += v * v;
  }
  partials[vb * 256 + c] = s;
  partials[vb * 256 + 128 + c] = q;
}

// ---- 10. reduce partials -> scale/shift ----------------------------------
__global__ __launch_bounds__(1024) void k_finalize(
    const float* __restrict__ partials,
    const float* __restrict__ gamma, const float* __restrict__ beta,
    float* __restrict__ ss)
{
  __shared__ float ls[8][128], lq[8][128];
  int c  = threadIdx.x & 127;
  int sl = threadIdx.x >> 7;   // 0..7
  float s = 0.f, q = 0.f;
  for (int b = sl * 128; b < (sl + 1) * 128; ++b) {
    s += partials[b * 256 + c];
    q += partials[b * 256 + 128 + c];
  }
  ls[sl][c] = s; lq[sl][c] = q;
  __syncthreads();
  if (sl == 0) {
    float S = 0.f, Q = 0.f;
#pragma unroll
    for (int i = 0; i < 8; ++i) { S += ls[i][c]; Q += lq[i][c]; }
    float mu  = S / (float)NN;
    float var = Q / (float)NN - mu * mu;
    float rsig = rsqrtf(var + BN_EPS);
    float sc = gamma[c] * rsig;
    float sh = beta[c] - mu * sc;
    ss[c] = sc;
    ss[128 + c] = sh;
  }
}

// ---- 11. in-place normalize ----------------------------------------------
__global__ __launch_bounds__(256) void k_norm(
    float* __restrict__ io, const float* __restrict__ ss)
{
  __shared__ float sc[128], sh[128];
  if (threadIdx.x < 128) {
    sc[threadIdx.x] = ss[threadIdx.x];
    sh[threadIdx.x] = ss[128 + threadIdx.x];
  }
  __syncthreads();
  const long total = (long)NN * DD / 4;
  for (long i = (long)blockIdx.x * blockDim.x + threadIdx.x; i < total;
       i += (long)gridDim.x * blockDim.x) {
    float4 v = *(const float4*)(io + i * 4);
    int c0 = (int)((i * 4) & (DD - 1));
    v.x = fmaf(v.x, sc[c0 + 0], sh[c0 + 0]);
    v.y = fmaf(v.y, sc[c0 + 1], sh[c0 + 1]);
    v.z = fmaf(v.z, sc[c0 + 2], sh[c0 + 2]);
    v.w = fmaf(v.w, sc[c0 + 3], sh[c0 + 3]);
    *(float4*)(io + i * 4) = v;
  }
}

extern "C" void kernel_launch(void* const* d_in, const int* in_sizes, int n_in,
                              void* d_out, int out_size, void* d_ws, size_t ws_size,
                              hipStream_t stream)
{
  const float* x     = (const float*)d_in[0];
  // d_in[1] = edge_attr — unused by the reference
  const float* Wl    = (const float*)d_in[2];
  const float* bl    = (const float*)d_in[3];
  const float* Wr    = (const float*)d_in[4];
  const float* gamma = (const float*)d_in[5];
  const float* beta  = (const float*)d_in[6];
  const int*   ei    = (const int*)d_in[7];
  float* out = (float*)d_out;

  char* ws = (char*)d_ws;
  unsigned short* magg   = (unsigned short*)(ws);              // 25,600,000 B
  int*            esrc   = (int*)(ws + 25600000);              //  2,560,000 B
  int*            deg    = (int*)(ws + 28160000);              //    400,384 B (NB*256)
  int*            offs   = (int*)(ws + 28560384);              //    400,384 B
  int*            bsum   = (int*)(ws + 28960768);              //      2,048 B
  int*            boff   = (int*)(ws + 28962816);              //      2,048 B
  unsigned short* wbf    = (unsigned short*)(ws + 28964864);   //     65,536 B
  float*          partials = (float*)(ws + 29030400);          //  1,048,576 B
  float*          ssbuf  = (float*)(ws + 30078976);            //      1,024 B
  (void)ws_size; (void)in_sizes; (void)n_in; (void)out_size;

  hipMemsetAsync(deg, 0, 400384, stream);
  k_prepw   <<<128,   256, 0, stream>>>(Wl, Wr, wbf);
  k_hist    <<<2500,  256, 0, stream>>>(ei, deg);
  k_scan1   <<<NB,    256, 0, stream>>>(deg, bsum);
  k_scan2   <<<1,     512, 0, stream>>>(bsum, boff);
  k_scan3   <<<NB,    256, 0, stream>>>(deg, boff, offs);
  k_fill    <<<2500,  256, 0, stream>>>(ei, deg, esrc);
  k_agg     <<<25000, 256, 0, stream>>>(x, offs, esrc, magg);
  k_gemm    <<<1563,  256, 0, stream>>>(x, magg, wbf, bl, out);
  k_colstats<<<512,   256, 0, stream>>>(out, partials);
  k_finalize<<<1,    1024, 0, stream>>>(partials, gamma, beta, ssbuf);
  k_norm    <<<2048,  256, 0, stream>>>(out, ssbuf);
}

// Round 4
// 227.414 us; speedup vs baseline: 3.4599x; 1.2894x over previous
//
#include <hip/hip_runtime.h>
#include <stdint.h>

#define NN 100000     // nodes
#define NE 640000     // edges
#define DD 128        // features
#define BN_EPS 1e-5f
#define NB 391        // scan blocks: 391*256 = 100096 >= NN
#define NROWPAD 100096
#define NTILE 782     // 128-row GEMM tiles: 782*128 = 100096

typedef __attribute__((ext_vector_type(8))) short bf16x8;
typedef __attribute__((ext_vector_type(4))) float f32x4;

static __device__ __forceinline__ float bf2f(unsigned short s) {
  return __uint_as_float(((unsigned)s) << 16);
}
static __device__ __forceinline__ unsigned short f2bf(float f) {
  unsigned u = __float_as_uint(f);
  u += 0x7FFFu + ((u >> 16) & 1u);   // RNE
  return (unsigned short)(u >> 16);
}

// ---- 1. weights -> bf16, wbf[col][0..255] = [Wl[col][:] | Wr[col][:]] ----
__global__ __launch_bounds__(256) void k_prepw(const float* __restrict__ Wl,
                                               const float* __restrict__ Wr,
                                               unsigned short* __restrict__ wbf)
{
  int i = blockIdx.x * 256 + threadIdx.x;   // grid 128 -> 32768
  int col = i >> 8, k = i & 255;
  float v = (k < DD) ? Wl[col * DD + k] : Wr[col * DD + (k - DD)];
  wbf[i] = f2bf(v);
}

// ---- 2. x-half of abuf: abuf[row][128+j] = bf16(relu(x[row][j])) ---------
__global__ __launch_bounds__(256) void k_prepx(const float* __restrict__ x,
                                               unsigned short* __restrict__ abuf)
{
  int i = blockIdx.x * 256 + threadIdx.x;   // 6250*256 = 1,600,000 = NN*16
  int row = i >> 4, cj = i & 15;
  if (row >= NN) return;
  const float* xp = x + (long)row * DD + cj * 8;
  float tmp[8];
  *(float4*)(tmp)     = *(const float4*)(xp);
  *(float4*)(tmp + 4) = *(const float4*)(xp + 4);
  bf16x8 o;
#pragma unroll
  for (int e = 0; e < 8; ++e) o[e] = (short)f2bf(fmaxf(tmp[e], 0.f));
  *(bf16x8*)(abuf + (long)row * 256 + DD + cj * 8) = o;
}

// ---- 3. degree histogram -------------------------------------------------
__global__ __launch_bounds__(256) void k_hist(const int* __restrict__ ei,
                                              int* __restrict__ deg)
{
  int e = blockIdx.x * 256 + threadIdx.x;
  if (e < NE) atomicAdd(deg + ei[NE + e], 1);
}

// ---- 4. block sums -------------------------------------------------------
__global__ __launch_bounds__(256) void k_scan1(const int* __restrict__ deg,
                                               int* __restrict__ bsum)
{
  __shared__ int sc[256];
  int t = threadIdx.x;
  sc[t] = deg[blockIdx.x * 256 + t];
  __syncthreads();
  for (int s = 128; s > 0; s >>= 1) {
    if (t < s) sc[t] += sc[t + s];
    __syncthreads();
  }
  if (t == 0) bsum[blockIdx.x] = sc[0];
}

// ---- 5. exclusive scan of block sums ------------------------------------
__global__ __launch_bounds__(512) void k_scan2(const int* __restrict__ bsum,
                                               int* __restrict__ boff)
{
  __shared__ int sc[512];
  int t = threadIdx.x;
  int v = (t < NB) ? bsum[t] : 0;
  sc[t] = v;
  __syncthreads();
  for (int s = 1; s < 512; s <<= 1) {
    int add = (t >= s) ? sc[t - s] : 0;
    __syncthreads();
    sc[t] += add;
    __syncthreads();
  }
  if (t < NB) boff[t] = sc[t] - v;
}

// ---- 6. per-element exclusive scan -> offs; deg becomes fill-cursor ------
__global__ __launch_bounds__(256) void k_scan3(int* __restrict__ deg,
                                               const int* __restrict__ boff,
                                               int* __restrict__ offs)
{
  __shared__ int sc[256];
  int t = threadIdx.x;
  int i = blockIdx.x * 256 + t;
  int v = deg[i];
  sc[t] = v;
  __syncthreads();
  for (int s = 1; s < 256; s <<= 1) {
    int add = (t >= s) ? sc[t - s] : 0;
    __syncthreads();
    sc[t] += add;
    __syncthreads();
  }
  int excl = sc[t] - v + boff[blockIdx.x];
  offs[i] = excl;
  deg[i]  = excl;
}

// ---- 7. fill CSR ---------------------------------------------------------
__global__ __launch_bounds__(256) void k_fill(const int* __restrict__ ei,
                                              int* __restrict__ cursor,
                                              int* __restrict__ esrc)
{
  int e = blockIdx.x * 256 + threadIdx.x;
  if (e >= NE) return;
  int pos = atomicAdd(cursor + ei[NE + e], 1);
  esrc[pos] = ei[e];
}

// ---- 8. gather-aggregate: abuf[dst][0..127] = bf16(mean(xbf[src])) -------
// one wave per dst; reads pre-relu'd bf16 half (256 B/edge).
__global__ __launch_bounds__(256) void k_agg(const int* __restrict__ offs,
                                             const int* __restrict__ esrc,
                                             unsigned short* __restrict__ abuf)
{
  int dst = blockIdx.x * 4 + (threadIdx.x >> 6);
  if (dst >= NN) return;
  int lane = threadIdx.x & 63;
  int off = offs[dst], end = offs[dst + 1];
  float ax = 0.f, ay = 0.f;
  for (int base = off; base < end; base += 64) {
    int m = end - base; if (m > 64) m = 64;
    int myidx = base + lane;
    int mysrc = (myidx < end) ? esrc[myidx] : 0;
    for (int j = 0; j < m; ++j) {
      int src = __shfl(mysrc, j);
      unsigned w = *(const unsigned*)(abuf + (long)src * 256 + DD + lane * 2);
      ax += bf2f((unsigned short)(w & 0xFFFFu));
      ay += bf2f((unsigned short)(w >> 16));
    }
  }
  float rinv = (end > off) ? 1.0f / (float)(end - off) : 0.f;
  unsigned pk = (unsigned)f2bf(ax * rinv) | ((unsigned)f2bf(ay * rinv) << 16);
  *(unsigned*)(abuf + (long)dst * 256 + lane * 2) = pk;
}

// ---- 9. GEMM: out = abuf[100096 x 256] @ wbf^T[256 x 128] + bl -----------
// 128x128 tile, BK=32, 4 waves (64x64 each), double-buffered reg-staged LDS.
// LDS chunk layout [kg][row|col][16B] -> 2-way (free) bank pattern on b128.
// mfma_f32_16x16x32_bf16: A/B lane: row|col = l&15, k = (l>>4)*8+e;
//                         C/D: col = l&15, row = (l>>4)*4 + reg.
// Epilogue fuses BN column stats (sum, sumsq) via per-lane regs + atomics.
__global__ __launch_bounds__(256) void k_gemm(
    const unsigned short* __restrict__ abuf,
    const unsigned short* __restrict__ wbf,
    const float* __restrict__ bl,
    float* __restrict__ out,
    float* __restrict__ ssum, float* __restrict__ qsum)
{
  __shared__ __align__(16) unsigned short lds[2][8192]; // [buf][A 4096us | B 4096us]
  const int t = threadIdx.x;
  const int lane = t & 63, wv = t >> 6;
  const int c15 = lane & 15, kg = lane >> 4;
  const int wrow = (wv & 1) * 64;
  const int wcol = (wv >> 1) * 64;

  float bias[4];
#pragma unroll
  for (int ct = 0; ct < 4; ++ct) bias[ct] = bl[wcol + ct * 16 + c15];

  float sS[4] = {0.f, 0.f, 0.f, 0.f}, sQ[4] = {0.f, 0.f, 0.f, 0.f};

  // staging decode: 4 chunks/thread/K-step; ids 0..511 = A, 512..1023 = B
  int ckg[4], crc[4]; bool cisA[4];
#pragma unroll
  for (int j = 0; j < 4; ++j) {
    int id = j * 256 + t;
    cisA[j] = id < 512;
    int m = id & 511;
    ckg[j] = m >> 7;          // 0..3
    crc[j] = m & 127;         // row (A) / col (B)
  }

  for (int tile = blockIdx.x; tile < NTILE; tile += gridDim.x) {
    const long tb = (long)tile * 128;
    f32x4 acc[4][4];
#pragma unroll
    for (int i = 0; i < 4; ++i)
#pragma unroll
      for (int j = 0; j < 4; ++j) acc[i][j] = (f32x4){0.f, 0.f, 0.f, 0.f};

    uint4 st[4];
#pragma unroll
    for (int j = 0; j < 4; ++j) {             // load ks=0
      const unsigned short* src = cisA[j]
          ? abuf + (tb + crc[j]) * 256 + ckg[j] * 8
          : wbf + (long)crc[j] * 256 + ckg[j] * 8;
      st[j] = *(const uint4*)src;
    }
#pragma unroll
    for (int j = 0; j < 4; ++j)               // write buf0
      *(uint4*)&lds[0][(j * 256 + t) * 8] = st[j];
#pragma unroll
    for (int j = 0; j < 4; ++j) {             // load ks=1
      const unsigned short* src = cisA[j]
          ? abuf + (tb + crc[j]) * 256 + 32 + ckg[j] * 8
          : wbf + (long)crc[j] * 256 + 32 + ckg[j] * 8;
      st[j] = *(const uint4*)src;
    }
    __syncthreads();

    for (int ks = 0; ks < 8; ++ks) {
      const int cur = ks & 1;
      if (ks < 7) {
#pragma unroll
        for (int j = 0; j < 4; ++j)           // write ks+1 into buf^1
          *(uint4*)&lds[cur ^ 1][(j * 256 + t) * 8] = st[j];
        if (ks < 6) {
          const int k2 = (ks + 2) * 32;
#pragma unroll
          for (int j = 0; j < 4; ++j) {       // issue loads for ks+2
            const unsigned short* src = cisA[j]
                ? abuf + (tb + crc[j]) * 256 + k2 + ckg[j] * 8
                : wbf + (long)crc[j] * 256 + k2 + ckg[j] * 8;
            st[j] = *(const uint4*)src;
          }
        }
      }
      bf16x8 af[4], bfr[4];
#pragma unroll
      for (int rs = 0; rs < 4; ++rs)
        af[rs] = *(const bf16x8*)&lds[cur][kg * 1024 + (wrow + rs * 16 + c15) * 8];
#pragma unroll
      for (int ct = 0; ct < 4; ++ct)
        bfr[ct] = *(const bf16x8*)&lds[cur][4096 + kg * 1024 + (wcol + ct * 16 + c15) * 8];
#pragma unroll
      for (int rs = 0; rs < 4; ++rs)
#pragma unroll
        for (int ct = 0; ct < 4; ++ct)
          acc[rs][ct] = __builtin_amdgcn_mfma_f32_16x16x32_bf16(af[rs], bfr[ct], acc[rs][ct], 0, 0, 0);
      __syncthreads();
    }

    // epilogue: bias add, store f32, accumulate BN stats
#pragma unroll
    for (int rs = 0; rs < 4; ++rs) {
      long row0 = tb + wrow + rs * 16 + kg * 4;
#pragma unroll
      for (int ct = 0; ct < 4; ++ct) {
        int col = wcol + ct * 16 + c15;
#pragma unroll
        for (int r = 0; r < 4; ++r) {
          long row = row0 + r;
          if (row < NN) {
            float v = acc[rs][ct][r] + bias[ct];
            out[row * DD + col] = v;
            sS[ct] += v;
            sQ[ct] += v * v;
          }
        }
      }
    }
  }

  // flush column stats: reduce over kg lane-groups, one atomic per col
#pragma unroll
  for (int ct = 0; ct < 4; ++ct) {
    float s = sS[ct], q = sQ[ct];
    s += __shfl_xor(s, 16); q += __shfl_xor(q, 16);
    s += __shfl_xor(s, 32); q += __shfl_xor(q, 32);
    if (lane < 16) {
      atomicAdd(&ssum[wcol + ct * 16 + lane], s);
      atomicAdd(&qsum[wcol + ct * 16 + lane], q);
    }
  }
}

// ---- 10. finalize BN scale/shift -----------------------------------------
__global__ __launch_bounds__(128) void k_finalize(
    const float* __restrict__ ssum, const float* __restrict__ qsum,
    const float* __restrict__ gamma, const float* __restrict__ beta,
    float* __restrict__ ss)
{
  int c = threadIdx.x;
  float mu  = ssum[c] / (float)NN;
  float var = qsum[c] / (float)NN - mu * mu;   // biased variance
  float rsig = rsqrtf(var + BN_EPS);
  float sc = gamma[c] * rsig;
  float sh = beta[c] - mu * sc;
  ss[c] = sc;
  ss[128 + c] = sh;
}

// ---- 11. in-place normalize ----------------------------------------------
__global__ __launch_bounds__(256) void k_norm(
    float* __restrict__ io, const float* __restrict__ ss)
{
  __shared__ float sc[128], sh[128];
  if (threadIdx.x < 128) {
    sc[threadIdx.x] = ss[threadIdx.x];
    sh[threadIdx.x] = ss[128 + threadIdx.x];
  }
  __syncthreads();
  const long total = (long)NN * DD / 4;
  for (long i = (long)blockIdx.x * blockDim.x + threadIdx.x; i < total;
       i += (long)gridDim.x * blockDim.x) {
    float4 v = *(const float4*)(io + i * 4);
    int c0 = (int)((i * 4) & (DD - 1));
    v.x = fmaf(v.x, sc[c0 + 0], sh[c0 + 0]);
    v.y = fmaf(v.y, sc[c0 + 1], sh[c0 + 1]);
    v.z = fmaf(v.z, sc[c0 + 2], sh[c0 + 2]);
    v.w = fmaf(v.w, sc[c0 + 3], sh[c0 + 3]);
    *(float4*)(io + i * 4) = v;
  }
}

extern "C" void kernel_launch(void* const* d_in, const int* in_sizes, int n_in,
                              void* d_out, int out_size, void* d_ws, size_t ws_size,
                              hipStream_t stream)
{
  const float* x     = (const float*)d_in[0];
  // d_in[1] = edge_attr — unused by the reference
  const float* Wl    = (const float*)d_in[2];
  const float* bl    = (const float*)d_in[3];
  const float* Wr    = (const float*)d_in[4];
  const float* gamma = (const float*)d_in[5];
  const float* beta  = (const float*)d_in[6];
  const int*   ei    = (const int*)d_in[7];
  float* out = (float*)d_out;

  char* ws = (char*)d_ws;
  unsigned short* abuf = (unsigned short*)(ws);            // 100096*256*2 = 51,249,152
  int*   esrc  = (int*)(ws + 51249152);                    //  2,560,000 -> 53,809,152
  int*   deg   = (int*)(ws + 53809152);                    //    400,384 -> 54,209,536
  float* ssum  = (float*)(ws + 54209536);                  //        512 -> 54,210,048
  float* qsum  = (float*)(ws + 54210048);                  //        512 -> 54,210,560
  int*   offs  = (int*)(ws + 54210560);                    //    400,384 -> 54,610,944
  int*   bsum  = (int*)(ws + 54610944);                    //      2,048 -> 54,612,992
  int*   boff  = (int*)(ws + 54612992);                    //      2,048 -> 54,615,040
  unsigned short* wbf = (unsigned short*)(ws + 54615040);  //     65,536 -> 54,680,576
  float* ssbuf = (float*)(ws + 54680576);                  //      1,024 -> 54,681,600
  (void)ws_size; (void)in_sizes; (void)n_in; (void)out_size;

  hipMemsetAsync(deg, 0, 401408, stream);            // deg + ssum + qsum
  hipMemsetAsync(ws + (long)NN * 512, 0, 49152, stream);   // abuf pad rows
  k_prepw   <<<128,   256, 0, stream>>>(Wl, Wr, wbf);
  k_prepx   <<<6250,  256, 0, stream>>>(x, abuf);
  k_hist    <<<2500,  256, 0, stream>>>(ei, deg);
  k_scan1   <<<NB,    256, 0, stream>>>(deg, bsum);
  k_scan2   <<<1,     512, 0, stream>>>(bsum, boff);
  k_scan3   <<<NB,    256, 0, stream>>>(deg, boff, offs);
  k_fill    <<<2500,  256, 0, stream>>>(ei, deg, esrc);
  k_agg     <<<25000, 256, 0, stream>>>(offs, esrc, abuf);
  k_gemm    <<<512,   256, 0, stream>>>(abuf, wbf, bl, out, ssum, qsum);
  k_finalize<<<1,     128, 0, stream>>>(ssum, qsum, gamma, beta, ssbuf);
  k_norm    <<<2048,  256, 0, stream>>>(out, ssbuf);
}